// Round 9
// baseline (157.108 us; speedup 1.0000x reference)
//
#include <hip/hip_runtime.h>
#include <hip/hip_bf16.h>

typedef __attribute__((ext_vector_type(8))) short bf16x8;
typedef __attribute__((ext_vector_type(4))) float f32x4;
typedef __attribute__((ext_vector_type(4))) unsigned int u32x4;

#define NB 32
#define NS 512
#define ND 1024

__device__ __forceinline__ unsigned short f2bf(float f) {
  unsigned int u = __float_as_uint(f);
  u = (u + 0x7FFFu + ((u >> 16) & 1u)) >> 16;  // RNE
  return (unsigned short)u;
}

__device__ __forceinline__ unsigned int pkbf(float lo, float hi) {
  __hip_bfloat162 h = __float22bfloat162_rn(make_float2(lo, hi));  // v_cvt_pk_bf16_f32 (RNE)
  union { __hip_bfloat162 h2; unsigned int u; } cv;
  cv.h2 = h;
  return cv.u;
}

// ---------- normalized aspect -> bf16 ----------
__global__ void anorm_kernel(const float* __restrict__ aspect,
                             unsigned short* __restrict__ a_n) {
  int b = blockIdx.x;
  int t = threadIdx.x;
  const float4* p = (const float4*)(aspect + (size_t)b * ND);
  float4 v = p[t];
  float s = v.x * v.x + v.y * v.y + v.z * v.z + v.w * v.w;
#pragma unroll
  for (int off = 32; off >= 1; off >>= 1) s += __shfl_down(s, off);
  __shared__ float red[4];
  if ((t & 63) == 0) red[t >> 6] = s;
  __syncthreads();
  float tot = red[0] + red[1] + red[2] + red[3];
  float inv = (tot > 0.f) ? (1.f / sqrtf(tot)) : 0.f;
  ushort4 u;
  u.x = f2bf(v.x * inv); u.y = f2bf(v.y * inv);
  u.z = f2bf(v.z * inv); u.w = f2bf(v.w * inv);
  ((ushort4*)(a_n + (size_t)b * ND))[t] = u;
}

// ---------- GEMM v12: norm fused (eN pass deleted), staging SPLIT across
// phases. Per tile: 4 MFMA phases, each followed by {vmcnt(2-oldest) ->
// cvt_pk one row-slice -> 1 ds_write_b128}. f32 loads for tile kt+1 issued at
// end of tile kt-1 -> full-tile latency. Counted lgkm ledger includes the
// interleaved writes: 4/5/5/1/0 (kt<15), peeled tail 4/4/4/0. B via LDS
// circulant copies (proven). 128x256, 4 waves, dbuf A, 2 blocks/CU (53.9 KB).
__global__ __launch_bounds__(256, 2)
void corr_gemm12_kernel(const float* __restrict__ emb,
                        const unsigned short* __restrict__ a_n,
                        float* __restrict__ out) {
  __shared__ __align__(16) unsigned short Abuf[2][128][64];   // 32 KB (bf16)
  __shared__ __align__(16) unsigned short copies[8 * 1288];   // 20.6 KB
  __shared__ float invnLDS[128];                              // 0.5 KB

  const int b = blockIdx.x, mt = blockIdx.y, nt = blockIdx.z;
  const int n0 = nt * 256, m0 = mt * 128;
  const int tid = threadIdx.x;

  const int lane = tid & 63, wn = tid >> 6;  // 4 waves = 4 col-quarters (128x64)
  const int q = lane >> 4, l16 = lane & 15;
  const int mx = l16 & 7;
  const int s00 = (q ^ mx) * 8;              // chunk q     (kk=0)
  const int s01 = ((4 + q) ^ mx) * 8;        // chunk 4+q   (kk=1)

  // B read base (v8 verbatim): addr = copies + pB*1287 + idx,
  // idx = kt*64 + kk*32 + 8q + 256 - n_local, idx&7 == pB.
  const int pB = (8 - mx) & 7;
  const unsigned short* Bp = copies + pB * 1287 + (256 + 8 * q - wn * 64 - l16);

  // A staging: thread t owns rows r0+32j (j=0..3), col-chunk cw (8 f32);
  // bf16 goes to LDS slot sw = cw ^ (r&7)  (r&7 == r0&7 since 32|32j).
  const int r0 = tid >> 3, cw = tid & 7;
  const int sw = cw ^ (r0 & 7);
  const float* gA = emb + ((size_t)b * NS + m0 + r0) * ND + cw * 8;

  // ---- prologue 1: gather a_n window into regs ----
  unsigned short av[40];
  {
    const unsigned short* an = a_n + (size_t)b * ND;
    const int p = tid & 7;
    const int x0 = (tid >> 3) * 40;  // 32 threads/copy x 40 = 1280
    const int base = (768 - n0 + p) & 1023;
#pragma unroll
    for (int j = 0; j < 40; ++j) av[j] = an[(base + x0 + j) & 1023];
  }

  float4 g[8];                       // staged f32 (2 float4 per row-slice)
  float ss0 = 0.f, ss1 = 0.f, ss2 = 0.f, ss3 = 0.f;  // per-row-slice sumsq

#define LOADG(KTT)                                                       \
  do {                                                                   \
    _Pragma("unroll")                                                    \
    for (int j = 0; j < 4; ++j) {                                        \
      const float* _p = gA + (size_t)j * 32 * ND + (KTT) * 64;           \
      g[2 * j] = *(const float4*)_p;                                     \
      g[2 * j + 1] = *(const float4*)(_p + 4);                           \
      __builtin_amdgcn_sched_barrier(0);  /* pin pair order for vmcnt */ \
    }                                                                    \
  } while (0)

#define CVT_J(NBUF, J, SS)                                               \
  do {                                                                   \
    float4 va = g[2 * (J)], vb = g[2 * (J) + 1];                         \
    SS += va.x * va.x + va.y * va.y + va.z * va.z + va.w * va.w          \
        + vb.x * vb.x + vb.y * vb.y + vb.z * vb.z + vb.w * vb.w;         \
    u32x4 w;                                                             \
    w[0] = pkbf(va.x, va.y);                                             \
    w[1] = pkbf(va.z, va.w);                                             \
    w[2] = pkbf(vb.x, vb.y);                                             \
    w[3] = pkbf(vb.z, vb.w);                                             \
    *(u32x4*)&Abuf[NBUF][r0 + 32 * (J)][sw * 8] = w;                     \
  } while (0)

  // ---- prologue 2: stage tile 0, write copies, cvt tile 0, load tile 1 ----
  LOADG(0);
  {
    const int p = tid & 7;
    const int x0 = (tid >> 3) * 40;
#pragma unroll
    for (int j = 0; j < 40; ++j) copies[p * 1288 + x0 + j] = av[j];
  }
  CVT_J(0, 0, ss0); CVT_J(0, 1, ss1); CVT_J(0, 2, ss2); CVT_J(0, 3, ss3);
  LOADG(1);
  __syncthreads();   // copies + Abuf[0] visible (drains vm too; once, ok)

  f32x4 acc[8][4];
#pragma unroll
  for (int i = 0; i < 8; ++i)
#pragma unroll
    for (int j = 0; j < 4; ++j)
      acc[i][j] = (f32x4){0.f, 0.f, 0.f, 0.f};

  bf16x8 a0[4], a1[4], bfr[4][2];

#define ISSUE_A(DST, BASE, PHN)                                             \
  do {                                                                      \
    DST[0] = *(const bf16x8*)&(BASE)[(PHN) * 32 + l16][s00];                \
    DST[1] = *(const bf16x8*)&(BASE)[(PHN) * 32 + l16][s01];                \
    DST[2] = *(const bf16x8*)&(BASE)[(PHN) * 32 + 16 + l16][s00];           \
    DST[3] = *(const bf16x8*)&(BASE)[(PHN) * 32 + 16 + l16][s01];           \
  } while (0)

#define LOAD_B(KTT)                                                 \
  do {                                                              \
    const unsigned short* Bt = Bp + (KTT) * 64;                     \
    _Pragma("unroll")                                               \
    for (int n = 0; n < 4; ++n) {                                   \
      bfr[n][0] = *(const bf16x8*)(Bt - n * 16);                    \
      bfr[n][1] = *(const bf16x8*)(Bt + 32 - n * 16);               \
    }                                                               \
  } while (0)

#define MFMA_PH(PH, CS)                                                                       \
  do {                                                                                        \
    __builtin_amdgcn_s_setprio(1);                                                            \
    _Pragma("unroll")                                                                         \
    for (int n = 0; n < 4; ++n) {                                                             \
      acc[2*(PH)][n]   = __builtin_amdgcn_mfma_f32_16x16x32_bf16(CS[0], bfr[n][0], acc[2*(PH)][n],   0, 0, 0); \
      acc[2*(PH)][n]   = __builtin_amdgcn_mfma_f32_16x16x32_bf16(CS[1], bfr[n][1], acc[2*(PH)][n],   0, 0, 0); \
      acc[2*(PH)+1][n] = __builtin_amdgcn_mfma_f32_16x16x32_bf16(CS[2], bfr[n][0], acc[2*(PH)+1][n], 0, 0, 0); \
      acc[2*(PH)+1][n] = __builtin_amdgcn_mfma_f32_16x16x32_bf16(CS[3], bfr[n][1], acc[2*(PH)+1][n], 0, 0, 0); \
    }                                                                                         \
    __builtin_amdgcn_s_setprio(0);                                                            \
  } while (0)

  // Invariant entering tile kt (0..14): Abuf[kt&1] ready (barrier), g[] holds
  // tile kt+1's f32 (8 vm in flight, pair-ordered), lgkm = 0.
#pragma unroll 1
  for (int kt = 0; kt < 15; ++kt) {
    const unsigned short (*At)[64] = Abuf[kt & 1];
    const int nb = (kt & 1) ^ 1;

    ISSUE_A(a0, At, 0);                         // 4 lgkm
    LOAD_B(kt);                                 // 8 lgkm
    __builtin_amdgcn_sched_barrier(0);          // pin a0+B as the 12 oldest
    ISSUE_A(a1, At, 1);                         // 4 lgkm -> 16
    asm volatile("s_waitcnt lgkmcnt(4)" ::: "memory");   // a0+B ready
    __builtin_amdgcn_sched_barrier(0);
    MFMA_PH(0, a0);

    asm volatile("s_waitcnt vmcnt(6)" ::: "memory");     // g0,g1 (full-tile old)
    __builtin_amdgcn_sched_barrier(0);
    CVT_J(nb, 0, ss0);                          // +W1 -> 5 outstanding
    ISSUE_A(a0, At, 2);                         // +4 -> 9
    asm volatile("s_waitcnt lgkmcnt(5)" ::: "memory");   // a1 (oldest 4) done
    __builtin_amdgcn_sched_barrier(0);
    MFMA_PH(1, a1);

    asm volatile("s_waitcnt vmcnt(4)" ::: "memory");     // g2,g3
    __builtin_amdgcn_sched_barrier(0);
    CVT_J(nb, 1, ss1);                          // +W2 -> 6
    ISSUE_A(a1, At, 3);                         // +4 -> 10
    asm volatile("s_waitcnt lgkmcnt(5)" ::: "memory");   // W1+a0(ph2) done
    __builtin_amdgcn_sched_barrier(0);
    MFMA_PH(2, a0);

    asm volatile("s_waitcnt vmcnt(2)" ::: "memory");     // g4,g5
    __builtin_amdgcn_sched_barrier(0);
    CVT_J(nb, 2, ss2);                          // +W3 -> 6
    asm volatile("s_waitcnt lgkmcnt(1)" ::: "memory");   // W2+a1(ph3) done
    __builtin_amdgcn_sched_barrier(0);
    MFMA_PH(3, a1);

    asm volatile("s_waitcnt vmcnt(0)" ::: "memory");     // g6,g7
    __builtin_amdgcn_sched_barrier(0);
    CVT_J(nb, 3, ss3);                          // +W4
    if (kt < 14) LOADG(kt + 2);                 // next f32 stage, full-tile window
    asm volatile("s_waitcnt lgkmcnt(0)" ::: "memory");   // W3,W4 done
    __builtin_amdgcn_sched_barrier(0);
    __builtin_amdgcn_s_barrier();               // tile seam (1 barrier/tile)
  }

  // ---- peeled tail kt=15 (no staging interleave) ----
  {
    const unsigned short (*At)[64] = Abuf[1];
    ISSUE_A(a0, At, 0);
    LOAD_B(15);
    __builtin_amdgcn_sched_barrier(0);
    ISSUE_A(a1, At, 1);
    asm volatile("s_waitcnt lgkmcnt(4)" ::: "memory");
    __builtin_amdgcn_sched_barrier(0);
    MFMA_PH(0, a0);
    ISSUE_A(a0, At, 2);
    asm volatile("s_waitcnt lgkmcnt(4)" ::: "memory");
    __builtin_amdgcn_sched_barrier(0);
    MFMA_PH(1, a1);
    ISSUE_A(a1, At, 3);
    asm volatile("s_waitcnt lgkmcnt(4)" ::: "memory");
    __builtin_amdgcn_sched_barrier(0);
    MFMA_PH(2, a0);
    asm volatile("s_waitcnt lgkmcnt(0)" ::: "memory");
    __builtin_amdgcn_sched_barrier(0);
    MFMA_PH(3, a1);
  }
#undef MFMA_PH
#undef LOAD_B
#undef ISSUE_A

  // ---- per-row inv-norm: reduce sumsq across the 8 stagers of each row ----
#pragma unroll
  for (int off = 4; off >= 1; off >>= 1) {
    ss0 += __shfl_xor(ss0, off);
    ss1 += __shfl_xor(ss1, off);
    ss2 += __shfl_xor(ss2, off);
    ss3 += __shfl_xor(ss3, off);
  }
  if ((lane & 7) == 0) {
    invnLDS[r0 +  0] = (ss0 > 0.f) ? (1.f / sqrtf(ss0)) : 0.f;
    invnLDS[r0 + 32] = (ss1 > 0.f) ? (1.f / sqrtf(ss1)) : 0.f;
    invnLDS[r0 + 64] = (ss2 > 0.f) ? (1.f / sqrtf(ss2)) : 0.f;
    invnLDS[r0 + 96] = (ss3 > 0.f) ? (1.f / sqrtf(ss3)) : 0.f;
  }
  __syncthreads();

  // epilogue: C/D layout col=lane&15, row=(lane>>4)*4+reg; scale by invn[row]
  float* outB = out + ((size_t)b * NS + m0) * ND + n0;
#pragma unroll
  for (int i = 0; i < 8; ++i) {
    f32x4 iv = *(const f32x4*)&invnLDS[i * 16 + q * 4];
#pragma unroll
    for (int rg = 0; rg < 4; ++rg) {
      int r = i * 16 + q * 4 + rg;
      float* orow = outB + (size_t)r * ND + wn * 64 + l16;
#pragma unroll
      for (int n = 0; n < 4; ++n)
        orow[n * 16] = acc[i][n][rg] * iv[rg];
    }
  }
#undef CVT_J
#undef LOADG
}

// ---------- small-ws fallback (round-1 kernels) ----------
__global__ void enorm_kernel(const float* __restrict__ emb,
                             float* __restrict__ inv_norm) {
  int wave = threadIdx.x >> 6;
  int lane = threadIdx.x & 63;
  int row = blockIdx.x * 4 + wave;
  const float4* p = (const float4*)(emb + (size_t)row * ND);
  float s = 0.f;
#pragma unroll
  for (int j = 0; j < 4; ++j) {
    float4 v = p[lane + 64 * j];
    s += v.x * v.x + v.y * v.y + v.z * v.z + v.w * v.w;
  }
#pragma unroll
  for (int off = 32; off >= 1; off >>= 1) s += __shfl_down(s, off);
  if (lane == 0) inv_norm[row] = (s > 0.f) ? (1.f / sqrtf(s)) : 0.f;
}

__global__ __launch_bounds__(256)
void corr_gemm_kernel(const float* __restrict__ emb,
                      const float* __restrict__ inv_norm,
                      const unsigned short* __restrict__ a_n,
                      float* __restrict__ out) {
  __shared__ unsigned short copies[8][2056];
  __shared__ unsigned short Atile[128][40];

  const int nt = blockIdx.x, mt = blockIdx.y, b = blockIdx.z;
  const int n0 = nt * 128, m0 = mt * 128;
  const int t = threadIdx.x;

  {
    const unsigned short* an = a_n + (size_t)b * ND;
    int p = t & 7;
    int x0 = (t >> 3) * 64;
#pragma unroll
    for (int j = 0; j < 64; j += 4) {
      ushort4 u;
      u.x = an[(x0 + j + 0 + p) & 1023];
      u.y = an[(x0 + j + 1 + p) & 1023];
      u.z = an[(x0 + j + 2 + p) & 1023];
      u.w = an[(x0 + j + 3 + p) & 1023];
      *(ushort4*)&copies[p][x0 + j] = u;
    }
  }

  const int ar = t >> 3;
  const int ac = (t & 7) * 4;
  float invn[4];
#pragma unroll
  for (int w = 0; w < 4; ++w)
    invn[w] = inv_norm[b * NS + m0 + ar + 32 * w];

  const int lane = t & 63;
  const int wv = t >> 6;
  const int wm = wv >> 1, wn = wv & 1;
  const int q = lane >> 4, l16 = lane & 15;

  f32x4 acc[4][4];
#pragma unroll
  for (int i = 0; i < 4; ++i)
#pragma unroll
    for (int j = 0; j < 4; ++j)
      acc[i][j] = (f32x4){0.f, 0.f, 0.f, 0.f};

  const float* embB = emb + ((size_t)b * NS + m0) * ND;

  for (int k0 = 0; k0 < ND; k0 += 32) {
    __syncthreads();
#pragma unroll
    for (int w = 0; w < 4; ++w) {
      int r = ar + 32 * w;
      float4 v = *(const float4*)(embB + (size_t)r * ND + k0 + ac);
      float in = invn[w];
      ushort4 u;
      u.x = f2bf(v.x * in); u.y = f2bf(v.y * in);
      u.z = f2bf(v.z * in); u.w = f2bf(v.w * in);
      *(ushort4*)&Atile[r][ac] = u;
    }
    __syncthreads();

    bf16x8 af[4], bfr[4];
#pragma unroll
    for (int r = 0; r < 4; ++r) {
      int m = wm * 64 + r * 16 + l16;
      af[r] = *(const bf16x8*)&Atile[m][q * 8];
    }
#pragma unroll
    for (int r = 0; r < 4; ++r) {
      int ng = n0 + wn * 64 + r * 16 + l16;
      int e0 = k0 + 8 * q - ng + 1024;
      int p = e0 & 7;
      bfr[r] = *(const bf16x8*)&copies[p][e0 - p];
    }
#pragma unroll
    for (int i = 0; i < 4; ++i)
#pragma unroll
      for (int j = 0; j < 4; ++j)
        acc[i][j] = __builtin_amdgcn_mfma_f32_16x16x32_bf16(af[i], bfr[j], acc[i][j], 0, 0, 0);
  }

  float* outB = out + ((size_t)b * NS + m0) * ND + n0;
#pragma unroll
  for (int i = 0; i < 4; ++i) {
#pragma unroll
    for (int rg = 0; rg < 4; ++rg) {
      int s = wm * 64 + i * 16 + q * 4 + rg;
      float* orow = outB + (size_t)s * ND + wn * 64 + l16;
#pragma unroll
      for (int j = 0; j < 4; ++j)
        orow[j * 16] = acc[i][j][rg];
    }
  }
}

extern "C" void kernel_launch(void* const* d_in, const int* in_sizes, int n_in,
                              void* d_out, int out_size, void* d_ws, size_t ws_size,
                              hipStream_t stream) {
  const float* emb = (const float*)d_in[0];
  const float* aspect = (const float*)d_in[1];
  float* out = (float*)d_out;

  if (ws_size >= 65536) {
    unsigned short* a_n = (unsigned short*)d_ws;
    anorm_kernel<<<NB, 256, 0, stream>>>(aspect, a_n);
    // grid (b, mt, nt): flat = b + 32*(mt + 4*nt) -> XCD = b%8; all 16 tiles
    // of batch b share an XCD -> emb panel + a_n L2 reuse across siblings.
    corr_gemm12_kernel<<<dim3(NB, 4, 4), 256, 0, stream>>>(emb, a_n, out);
  } else {
    float* inv_norm = (float*)d_ws;
    unsigned short* a_n = (unsigned short*)((char*)d_ws + 65536);
    enorm_kernel<<<4096, 256, 0, stream>>>(emb, inv_norm);
    anorm_kernel<<<NB, 256, 0, stream>>>(aspect, a_n);
    corr_gemm_kernel<<<dim3(8, 4, NB), 256, 0, stream>>>(emb, inv_norm, a_n, out);
  }
}